// Round 3
// baseline (1408.750 us; speedup 1.0000x reference)
//
#include <hip/hip_runtime.h>

#define HH 192
#define WW 192
#define BATCH 16
#define PLANE (HH*WW)              /* 36864 */
#define NELEM (BATCH*2*PLANE)      /* 1179648 */

// Tile: 96 px wide x 8 rows, 256 threads, 3 px per thread. Halo 2 each side.
// Grid = (2,24,16) = 768 blocks = exactly 3 blocks/CU at launch_bounds(256,3)
// -> all blocks co-resident, so a software grid barrier is safe (no deadlock).
#define TILEX 96
#define TILEY 8
#define SW 100  /* TILEX + 4 */
#define SH2 12  /* TILEY + 4 */
#define NSTAGE (2*SH2*SW)   /* 2400 */
#define NBLOCKS 768
#define DTF 0.2f
#define DTH 0.1f

// Workspace layout (floats): [0..199] K8T (tap-major [25][8]);
// [256] barrier count; [288] barrier generation; [1024..] bufA, bufH.
__global__ void prep_kernel(const float* __restrict__ kern, float* __restrict__ ws) {
    int t = blockIdx.x * blockDim.x + threadIdx.x;
    if (t < 200) {
        const float inv  = 1.0f / 0.0327249f;
        const float inv2 = inv * inv;
        const float sc[6] = {1.0f, inv, inv, inv2, inv2, inv2};
        int o = t / 8, j = t % 8, dy = o / 5, dx = o % 5;
        float v;
        if (j < 6)       v =  kern[j*25 + dy*5 + dx] * sc[j];
        else if (j == 6) v = -kern[1*25 + dy*5 + (4-dx)] * sc[1];
        else             v = -kern[2*25 + (4-dy)*5 + dx] * sc[2];
        ws[o*8 + j] = v;
    } else if (t < 264) {
        // zero barrier words (count at +256, gen at +288, both 128B-line separated)
        ((unsigned*)(ws + 256))[t - 200] = 0u;
    }
}

// Sense-reversal grid barrier. Device-scope atomics + threadfence handle
// cross-XCD L2 visibility (G16): release side does agent-scope writeback,
// acquire side invalidates, and the release/acquire chain count->gen is
// transitively ordered. Requires all NBLOCKS co-resident (guaranteed above).
__device__ __forceinline__ void grid_barrier(unsigned* cnt, unsigned* gen) {
    __syncthreads();
    if (threadIdx.x == 0) {
        unsigned g = __hip_atomic_load(gen, __ATOMIC_RELAXED, __HIP_MEMORY_SCOPE_AGENT);
        __threadfence();   // flush this block's stores (agent scope)
        unsigned a = __hip_atomic_fetch_add(cnt, 1u, __ATOMIC_ACQ_REL, __HIP_MEMORY_SCOPE_AGENT);
        if (a == NBLOCKS - 1u) {
            __hip_atomic_store(cnt, 0u, __ATOMIC_RELAXED, __HIP_MEMORY_SCOPE_AGENT);
            __hip_atomic_fetch_add(gen, 1u, __ATOMIC_RELEASE, __HIP_MEMORY_SCOPE_AGENT);
        } else {
            while (__hip_atomic_load(gen, __ATOMIC_ACQUIRE, __HIP_MEMORY_SCOPE_AGENT) == g)
                __builtin_amdgcn_s_sleep(2);
        }
        __threadfence();   // acquire side: invalidate stale lines before reads
    }
    __syncthreads();
}

// All 10 RHS evals (5 RK2 midpoint steps) in ONE kernel. Per eval:
// stage uin tile -> conv (D[3][2][8]) -> upwind select -> forward poly ->
// uout = ubase + alpha*rhs. ubase is carried in REGISTERS: each thread's base
// value equals the value it wrote at the last full step (bit-exact), so no
// global ubase reads at all. Weights are s_loaded once (loop-invariant).
__global__ __launch_bounds__(256, 3) void mega_kernel(
    const float* __restrict__ init,
    float* __restrict__ finalout,
    float* __restrict__ ws,
    const float* __restrict__ pw0, const float* __restrict__ pb0,
    const float* __restrict__ pw1, const float* __restrict__ pb1,
    const float* __restrict__ pwf, const float* __restrict__ pbf)
{
    const float* K8T = ws;
    unsigned* cnt = (unsigned*)(ws + 256);
    unsigned* gen = (unsigned*)(ws + 288);
    float* bufA = ws + 1024;
    float* bufH = bufA + NELEM;

    __shared__ float sh[2][SH2][SW];
    const int b   = blockIdx.z;
    const int ty0 = blockIdx.y * TILEY;
    const int tx0 = blockIdx.x * TILEX;
    const int tid = threadIdx.x;
    const int cy  = tid >> 5;           // 0..7
    const int x3  = (tid & 31) * 3;     // 0,3,..,93
    const size_t bo  = (size_t)b * 2 * PLANE;
    const size_t o0i = bo + (size_t)(ty0 + cy) * WW + (tx0 + x3);

    float base0[3], base1[3];           // u_base at this thread's 3+3 pixels

    #pragma unroll 1
    for (int s = 0; s < 10; ++s) {
        const float* uin; float* uout; float alpha;
        if (s == 0)      { uin = init; uout = bufH;                       alpha = DTH; }
        else if (s == 1) { uin = bufH; uout = bufA;                       alpha = DTF; }
        else if (s & 1)  { uin = bufH; uout = (s == 9) ? finalout : bufA; alpha = DTF; }
        else             { uin = bufA; uout = bufH;                       alpha = DTH; }

        // ---- Staging: 2400 elems over 256 threads (9-10 each).
        const float* uin_b = uin + bo;
        for (int i = tid; i < NSTAGE; i += 256) {
            const int ch  = (i >= SH2*SW) ? 1 : 0;
            const int j   = i - ch * (SH2*SW);
            const int ly  = j / SW;
            const int col = j - ly * SW;
            int gy = ty0 + ly - 2;  if (gy < 0) gy += HH; else if (gy >= HH) gy -= HH;
            int gx = tx0 + col - 2; if (gx < 0) gx += WW; else if (gx >= WW) gx -= WW;
            sh[ch][ly][col] = uin_b[ch*PLANE + gy*WW + gx];
        }
        __syncthreads();

        if (s == 0) {
            // base = init values = staged center pixels (uin==init here)
            #pragma unroll
            for (int p = 0; p < 3; ++p) {
                base0[p] = sh[0][cy+2][x3+2+p];
                base1[p] = sh[1][cy+2][x3+2+p];
            }
        }

        // ---- Conv: D[px][ch][j], dy loop rolled (code size).
        float D[3][2][8];
        #pragma unroll
        for (int p = 0; p < 3; ++p)
            #pragma unroll
            for (int c = 0; c < 2; ++c)
                #pragma unroll
                for (int j = 0; j < 8; ++j)
                    D[p][c][j] = 0.0f;

        #pragma unroll
        for (int c = 0; c < 2; ++c) {
            #pragma unroll 1
            for (int dy = 0; dy < 5; ++dy) {
                float row[7];
                #pragma unroll
                for (int dx = 0; dx < 7; ++dx)
                    row[dx] = sh[c][cy + dy][x3 + dx];
                const float* Kt = K8T + dy * 40;   // 5 taps x 8 weights
                #pragma unroll
                for (int dx = 0; dx < 5; ++dx) {
                    #pragma unroll
                    for (int j = 0; j < 8; ++j) {
                        const float w = Kt[dx*8 + j];
                        D[0][c][j] += row[dx]   * w;
                        D[1][c][j] += row[dx+1] * w;
                        D[2][c][j] += row[dx+2] * w;
                    }
                }
            }
        }

#define ZF(p,i) D[p][(i)/6][(i)%6]

        // ---- Upwind: d(poly_k)/dz at BASE z for both k, selections into
        // named regs (no xs copy; gradients for k=1 must see unmodified base).
        float s01[3], s02[3], s11[3], s12[3];
        #pragma unroll 1
        for (int k = 0; k < 2; ++k) {
            const float* W0 = pw0 + k*24;   // [2][12]
            const float* B0 = pb0 + k*2;
            const float* W1 = pw1 + k*26;   // [2][13]
            const float* B1 = pb1 + k*2;
            const float* WF = pwf + k*14;   // [14]
            const int i1 = k*6 + 1, i2 = k*6 + 2;

            float o0[3], o1[3], q0[3], q1[3];
            #pragma unroll
            for (int p = 0; p < 3; ++p) { o0[p] = B0[0]; o1[p] = B0[1]; }
            #pragma unroll
            for (int i = 0; i < 12; ++i) {
                const float wa = W0[i], wb = W0[12+i];
                #pragma unroll
                for (int p = 0; p < 3; ++p) {
                    o0[p] += wa * ZF(p, i);
                    o1[p] += wb * ZF(p, i);
                }
            }
            #pragma unroll
            for (int p = 0; p < 3; ++p) {
                const float pp = o0[p]*o1[p];
                q0[p] = B1[0] + W1[12]*pp;
                q1[p] = B1[1] + W1[25]*pp;
            }
            #pragma unroll
            for (int i = 0; i < 12; ++i) {
                const float wa = W1[i], wb = W1[13+i];
                #pragma unroll
                for (int p = 0; p < 3; ++p) {
                    q0[p] += wa * ZF(p, i);
                    q1[p] += wb * ZF(p, i);
                }
            }

            const float w0a1 = W0[i1], w0b1 = W0[12+i1];
            const float w1a1 = W1[i1], w1b1 = W1[13+i1];
            const float wf1  = WF[i1];
            const float w0a2 = W0[i2], w0b2 = W0[12+i2];
            const float w1a2 = W1[i2], w1b2 = W1[13+i2];
            const float wf2  = WF[i2];
            const float w112 = W1[12], w125 = W1[25], wf12 = WF[12], wf13 = WF[13];

            float g1[3], g2[3];
            #pragma unroll
            for (int p = 0; p < 3; ++p) {
                const float t1 = o1[p]*w0a1 + o0[p]*w0b1;
                g1[p] = wf1 + wf12*t1
                    + wf13*(q1[p]*(w1a1 + w112*t1) + q0[p]*(w1b1 + w125*t1));
                const float t2 = o1[p]*w0a2 + o0[p]*w0b2;
                g2[p] = wf2 + wf12*t2
                    + wf13*(q1[p]*(w1a2 + w112*t2) + q0[p]*(w1b2 + w125*t2));
            }

            if (k == 0) {
                #pragma unroll
                for (int p = 0; p < 3; ++p) {
                    s01[p] = (g1[p] > 0.0f) ? ZF(p,1) : D[p][0][6];
                    s02[p] = (g2[p] > 0.0f) ? ZF(p,2) : D[p][0][7];
                }
            } else {
                #pragma unroll
                for (int p = 0; p < 3; ++p) {
                    s11[p] = (g1[p] > 0.0f) ? ZF(p,7) : D[p][1][6];
                    s12[p] = (g2[p] > 0.0f) ? ZF(p,8) : D[p][1][7];
                }
            }
        }

        // Selected features: compile-time fold (i is constant after unroll).
#define XS(p,i) ((i)==1 ? s01[p] : (i)==2 ? s02[p] : (i)==7 ? s11[p] : (i)==8 ? s12[p] : ZF(p,(i)))

        // ---- Forward poly at selected features. k loop rolled.
        float res0[3], res1[3];
        #pragma unroll 1
        for (int k = 0; k < 2; ++k) {
            const float* W0 = pw0 + k*24;
            const float* B0 = pb0 + k*2;
            const float* W1 = pw1 + k*26;
            const float* B1 = pb1 + k*2;
            const float* WF = pwf + k*14;
            const float* BF = pbf + k;

            float o0[3], o1[3], q0[3], q1[3], y[3];
            #pragma unroll
            for (int p = 0; p < 3; ++p) { o0[p] = B0[0]; o1[p] = B0[1]; }
            #pragma unroll
            for (int i = 0; i < 12; ++i) {
                const float wa = W0[i], wb = W0[12+i];
                #pragma unroll
                for (int p = 0; p < 3; ++p) {
                    o0[p] += wa * XS(p, i);
                    o1[p] += wb * XS(p, i);
                }
            }
            #pragma unroll
            for (int p = 0; p < 3; ++p) {
                const float pp = o0[p]*o1[p];
                q0[p] = B1[0] + W1[12]*pp;
                q1[p] = B1[1] + W1[25]*pp;
                y[p]  = BF[0] + WF[12]*pp;
            }
            #pragma unroll
            for (int i = 0; i < 12; ++i) {
                const float wa = W1[i], wb = W1[13+i], wc = WF[i];
                #pragma unroll
                for (int p = 0; p < 3; ++p) {
                    q0[p] += wa * XS(p, i);
                    q1[p] += wb * XS(p, i);
                    y[p]  += wc * XS(p, i);
                }
            }
            const float wf13 = WF[13];
            if (k == 0) {
                #pragma unroll
                for (int p = 0; p < 3; ++p) res0[p] = y[p] + wf13*(q0[p]*q1[p]);
            } else {
                #pragma unroll
                for (int p = 0; p < 3; ++p) res1[p] = y[p] + wf13*(q0[p]*q1[p]);
            }
        }

        // ---- Write + carry base in registers (bit-exact vs re-reading).
        #pragma unroll
        for (int p = 0; p < 3; ++p) {
            const float w0v = base0[p] + alpha * res0[p];
            const float w1v = base1[p] + alpha * res1[p];
            uout[o0i + p]         = w0v;
            uout[o0i + PLANE + p] = w1v;
            if (s & 1) { base0[p] = w0v; base1[p] = w1v; }  // u_n update
        }

        if (s < 9) grid_barrier(cnt, gen);
    }
}

extern "C" void kernel_launch(void* const* d_in, const int* in_sizes, int n_in,
                              void* d_out, int out_size, void* d_ws, size_t ws_size,
                              hipStream_t stream)
{
    const float* init = (const float*)d_in[0];
    const float* kern = (const float*)d_in[1];
    const float* pw0  = (const float*)d_in[2];
    const float* pb0  = (const float*)d_in[3];
    const float* pw1  = (const float*)d_in[4];
    const float* pb1  = (const float*)d_in[5];
    const float* pwf  = (const float*)d_in[6];
    const float* pbf  = (const float*)d_in[7];
    float* out = (float*)d_out;
    float* ws  = (float*)d_ws;

    prep_kernel<<<dim3(1), dim3(320), 0, stream>>>(kern, ws);

    const dim3 grid(WW/TILEX, HH/TILEY, BATCH);   // (2, 24, 16) = 768 blocks
    mega_kernel<<<grid, dim3(256), 0, stream>>>(init, out, ws,
                                                pw0, pb0, pw1, pb1, pwf, pbf);
}

// Round 5
// 201.268 us; speedup vs baseline: 6.9994x; 6.9994x over previous
//
#include <hip/hip_runtime.h>

typedef float v2f __attribute__((ext_vector_type(2)));

#define HH 192
#define WW 192
#define BATCH 16
#define PLANE (HH*WW)              /* 36864 */
#define NELEM (BATCH*2*PLANE)      /* 1179648 */

// Tile: 96 px wide x 8 rows, 256 threads, 3 px per thread. Halo 2 each side.
// Grid = (2,24,16) = 768 blocks = exactly 3 blocks/CU.
#define TILEX 96
#define TILEY 8
#define SW 100  /* TILEX + 4 */
#define SH2 12  /* TILEY + 4 */
#define NSITE (SH2*SW)   /* 1200 sites, both channels staged together */

// Workspace: [0..200) K8T conv weights (tap-major [25][8]);
// [256..414) PP packed poly weight PAIRS as v2f {k=0, k=1};
// bufA at ws+512, bufH after.
//
// PP index map (v2f units):
//  0..11  W0a[i]={pw0[i],pw0[24+i]}      12..23 W0b[i]={pw0[12+i],pw0[36+i]}
//  24 B0a={pb0[0],pb0[2]}  25 B0b={pb0[1],pb0[3]}
//  26..37 W1a[i]={pw1[i],pw1[26+i]}      38..49 W1b[i]={pw1[13+i],pw1[39+i]}
//  50 W112={pw1[12],pw1[38]}  51 W125={pw1[25],pw1[51]}
//  52 B1a={pb1[0],pb1[2]}  53 B1b={pb1[1],pb1[3]}
//  54..67 WF[i]={pwf[i],pwf[14+i]}  (66=WF12, 67=WF13)
//  68 BF={pbf[0],pbf[1]}
//  69,70 GW0a = {W0k[i1_k]} for i1=(1|7), i2=(2|8)
//  71,72 GW0b = {W0k[12+i1_k]}
//  73,74 GW1a  75,76 GW1b  77,78 GWF  (same pattern, W1/WF rows)
__global__ void prep_kernel(const float* __restrict__ kern,
                            const float* __restrict__ pw0, const float* __restrict__ pb0,
                            const float* __restrict__ pw1, const float* __restrict__ pb1,
                            const float* __restrict__ pwf, const float* __restrict__ pbf,
                            float* __restrict__ ws)
{
    int t = blockIdx.x * blockDim.x + threadIdx.x;
    if (t < 200) {
        const float inv  = 1.0f / 0.0327249f;
        const float inv2 = inv * inv;
        const float sc[6] = {1.0f, inv, inv, inv2, inv2, inv2};
        int o = t / 8, j = t % 8, dy = o / 5, dx = o % 5;
        float v;
        if (j < 6)       v =  kern[j*25 + dy*5 + dx] * sc[j];
        else if (j == 6) v = -kern[1*25 + dy*5 + (4-dx)] * sc[1];
        else             v = -kern[2*25 + (4-dy)*5 + dx] * sc[2];
        ws[o*8 + j] = v;
    } else if (t < 279) {
        int p = t - 200;
        int arr, a, b;
        if (p < 12)       { arr=0; a=p;      b=24+p; }
        else if (p < 24)  { int i=p-12; arr=0; a=12+i; b=36+i; }
        else if (p == 24) { arr=1; a=0; b=2; }
        else if (p == 25) { arr=1; a=1; b=3; }
        else if (p < 38)  { int i=p-26; arr=2; a=i;    b=26+i; }
        else if (p < 50)  { int i=p-38; arr=2; a=13+i; b=39+i; }
        else if (p == 50) { arr=2; a=12; b=38; }
        else if (p == 51) { arr=2; a=25; b=51; }
        else if (p == 52) { arr=3; a=0; b=2; }
        else if (p == 53) { arr=3; a=1; b=3; }
        else if (p < 68)  { int i=p-54; arr=4; a=i; b=14+i; }
        else if (p == 68) { arr=5; a=0; b=1; }
        else {
            const signed char   A0[10] = {1,2,13,14,1,2,14,15,1,2};
            const signed char   A1[10] = {31,32,43,44,33,34,46,47,21,22};
            const unsigned char AR[10] = {0,0,0,0,2,2,2,2,4,4};
            int i = p - 69; arr = AR[i]; a = A0[i]; b = A1[i];
        }
        const float* bases[6] = {pw0, pb0, pw1, pb1, pwf, pbf};
        v2f v; v[0] = bases[arr][a]; v[1] = bases[arr][b];
        ((v2f*)(ws + 256))[p] = v;
    }
}

// One RHS eval fused with axpy: uout = ubase + alpha * rhs(uin).
// PACKED-FP32 version: conv packs the 2 input channels per v_pk_fma_f32
// (LDS tile channel-interleaved, ds_read_b64); poly packs the 2 output
// channels k (weight pairs pre-packed in PP, base features shared by both k).
// Per-component accumulation order identical to the scalar version.
__global__ __launch_bounds__(256, 3) void rhs_kernel(
    const float* __restrict__ uin,
    const float* __restrict__ ubase,
    float* __restrict__ uout,
    const float* __restrict__ ws,
    float alpha)
{
    const float* K8T = ws;
    const v2f* PP = (const v2f*)(ws + 256);

    __shared__ v2f sh[SH2][SW];
    const int b   = blockIdx.z;
    const int ty0 = blockIdx.y * TILEY;
    const int tx0 = blockIdx.x * TILEX;
    const int tid = threadIdx.x;
    const size_t bo = (size_t)b * 2 * PLANE;

    // ---- Staging: 1200 sites (both channels per site), 5 iters/thread.
    const float* uin_b = uin + bo;
    for (int i = tid; i < NSITE; i += 256) {
        const int ly  = i / SW;
        const int col = i - ly * SW;
        int gy = ty0 + ly - 2;  if (gy < 0) gy += HH; else if (gy >= HH) gy -= HH;
        int gx = tx0 + col - 2; if (gx < 0) gx += WW; else if (gx >= WW) gx -= WW;
        const int gi = gy*WW + gx;
        v2f v; v[0] = uin_b[gi]; v[1] = uin_b[PLANE + gi];
        sh[ly][col] = v;
    }
    __syncthreads();

    const int cy = tid >> 5;            // 0..7
    const int x3 = (tid & 31) * 3;      // 0,3,..,93

    // ---- Conv: D2[px][j] = v2f over channels. dy loop rolled (code size).
    v2f D2[3][8];
    #pragma unroll
    for (int p = 0; p < 3; ++p)
        #pragma unroll
        for (int j = 0; j < 8; ++j)
            D2[p][j] = (v2f){0.0f, 0.0f};

    #pragma unroll 1
    for (int dy = 0; dy < 5; ++dy) {
        v2f row[7];
        #pragma unroll
        for (int dx = 0; dx < 7; ++dx)
            row[dx] = sh[cy + dy][x3 + dx];
        const float* Kt = K8T + dy * 40;   // 5 taps x 8 weights
        #pragma unroll
        for (int dx = 0; dx < 5; ++dx) {
            #pragma unroll
            for (int j = 0; j < 8; ++j) {
                const float w = Kt[dx*8 + j];
                D2[0][j] += row[dx]   * w;   // v_pk_fma_f32: both channels
                D2[1][j] += row[dx+1] * w;
                D2[2][j] += row[dx+2] * w;
            }
        }
    }

    // Feature i of pixel p: channel = i/6, map = i%6.
#define Z(p,i) (D2[p][(i)%6][(i)/6])

    v2f res[3];   // {k=0, k=1} per pixel
    #pragma unroll
    for (int p = 0; p < 3; ++p) {
        // ---- Base pass, packed over k (base features identical for both k).
        v2f o0 = PP[24], o1 = PP[25];
        #pragma unroll
        for (int i = 0; i < 12; ++i) {
            const float zv = Z(p, i);
            o0 += PP[i]    * zv;
            o1 += PP[12+i] * zv;
        }
        const v2f pb = o0 * o1;
        v2f q0 = PP[52] + PP[50]*pb;
        v2f q1 = PP[53] + PP[51]*pb;
        #pragma unroll
        for (int i = 0; i < 12; ++i) {
            const float zv = Z(p, i);
            q0 += PP[26+i] * zv;
            q1 += PP[38+i] * zv;
        }

        // ---- Gradients at the two upwind-selectable features, packed over k.
        const v2f t1 = o1*PP[69] + o0*PP[71];
        const v2f g1 = PP[77] + PP[66]*t1
            + PP[67]*(q1*(PP[73] + PP[50]*t1) + q0*(PP[75] + PP[51]*t1));
        const v2f t2 = o1*PP[70] + o0*PP[72];
        const v2f g2 = PP[78] + PP[66]*t2
            + PP[67]*(q1*(PP[74] + PP[50]*t2) + q0*(PP[76] + PP[51]*t2));

        // Selections (shared feature vector: all 4 replacements visible to both k).
        const float s1 = (g1[0] > 0.0f) ? Z(p,1) : D2[p][6][0];
        const float s2 = (g2[0] > 0.0f) ? Z(p,2) : D2[p][7][0];
        const float s3 = (g1[1] > 0.0f) ? Z(p,7) : D2[p][6][1];
        const float s4 = (g2[1] > 0.0f) ? Z(p,8) : D2[p][7][1];
#define XV(i) ((i)==1 ? s1 : (i)==2 ? s2 : (i)==7 ? s3 : (i)==8 ? s4 : Z(p,(i)))

        // ---- Forward poly at selected features, packed over k.
        v2f f0 = PP[24], f1 = PP[25];
        #pragma unroll
        for (int i = 0; i < 12; ++i) {
            const float xv = XV(i);
            f0 += PP[i]    * xv;
            f1 += PP[12+i] * xv;
        }
        const v2f pf = f0 * f1;
        v2f r0 = PP[52] + PP[50]*pf;
        v2f r1 = PP[53] + PP[51]*pf;
        v2f y  = PP[68] + PP[66]*pf;
        #pragma unroll
        for (int i = 0; i < 12; ++i) {
            const float xv = XV(i);
            r0 += PP[26+i] * xv;
            r1 += PP[38+i] * xv;
            y  += PP[54+i] * xv;
        }
        res[p] = y + PP[67]*(r0*r1);
#undef XV
    }

    const int oy = ty0 + cy, ox = tx0 + x3;
    const size_t o0i = bo + (size_t)oy * WW + ox;
    #pragma unroll
    for (int p = 0; p < 3; ++p) {
        uout[o0i + p]         = ubase[o0i + p]         + alpha * res[p][0];
        uout[o0i + PLANE + p] = ubase[o0i + PLANE + p] + alpha * res[p][1];
    }
}

extern "C" void kernel_launch(void* const* d_in, const int* in_sizes, int n_in,
                              void* d_out, int out_size, void* d_ws, size_t ws_size,
                              hipStream_t stream)
{
    const float* init = (const float*)d_in[0];
    const float* kern = (const float*)d_in[1];
    const float* pw0  = (const float*)d_in[2];
    const float* pb0  = (const float*)d_in[3];
    const float* pw1  = (const float*)d_in[4];
    const float* pb1  = (const float*)d_in[5];
    const float* pwf  = (const float*)d_in[6];
    const float* pbf  = (const float*)d_in[7];
    float* out = (float*)d_out;
    float* ws  = (float*)d_ws;

    float* bufA = ws + 512;            // NELEM floats: u_n
    float* bufH = bufA + NELEM;        // NELEM floats: u_half

    prep_kernel<<<dim3(1), dim3(320), 0, stream>>>(kern, pw0, pb0, pw1, pb1, pwf, pbf, ws);

    const dim3 grid(WW/TILEX, HH/TILEY, BATCH);   // (2, 24, 16) = 768 blocks
    const dim3 block(256);
    const float DTF = 0.2f, DTH = 0.1f;

    // T=1 -> 5 RK2 (midpoint) steps, 2 RHS evals each (sequential dependency).
    rhs_kernel<<<grid, block, 0, stream>>>(init, init, bufH, ws, DTH);
    rhs_kernel<<<grid, block, 0, stream>>>(bufH, init, bufA, ws, DTF);
    for (int s = 0; s < 3; ++s) {
        rhs_kernel<<<grid, block, 0, stream>>>(bufA, bufA, bufH, ws, DTH);
        rhs_kernel<<<grid, block, 0, stream>>>(bufH, bufA, bufA, ws, DTF);
    }
    rhs_kernel<<<grid, block, 0, stream>>>(bufA, bufA, bufH, ws, DTH);
    rhs_kernel<<<grid, block, 0, stream>>>(bufH, bufA, out,  ws, DTF);
}